// Round 7
// baseline (4633.118 us; speedup 1.0000x reference)
//
#include <hip/hip_runtime.h>

#define HID 512
#define TSTEPS 1024

typedef short bf16x8 __attribute__((ext_vector_type(8)));
typedef float fx4 __attribute__((ext_vector_type(4)));
typedef unsigned ux2 __attribute__((ext_vector_type(2)));

__device__ __forceinline__ short f2bf(float f) {
  unsigned u = __builtin_bit_cast(unsigned, f);
  u = (u + 0x7fffu + ((u >> 16) & 1u)) >> 16;   // RNE
  return (short)u;
}

// ---------------- Kernel A: vin = x @ W_in + b_in + b_hid  (into d_out) ----------------
__global__ __launch_bounds__(256) void vin_gemm(
    const float* __restrict__ x, const float* __restrict__ W_in,
    const float* __restrict__ b_in, const float* __restrict__ b_hid,
    float* __restrict__ out)
{
  __shared__ __align__(16) char smA[128 * 32 * 2];
  __shared__ __align__(16) char smB[128 * 32 * 2];
  const int tid = threadIdx.x;
  const int wave = tid >> 6, lane = tid & 63;
  const int lg = lane >> 4, lr = lane & 15;
  const int wm = wave >> 1, wn = wave & 1;
  const int r0 = blockIdx.x * 128, c0 = blockIdx.y * 128;

  fx4 acc[4][4] = {};
  const int arow = tid >> 3, aseg = tid & 7;
  const int bk = tid >> 3, bq = tid & 7;

  for (int k0 = 0; k0 < 256; k0 += 32) {
    #pragma unroll
    for (int q = 0; q < 4; ++q) {
      int row = arow + q * 32;
      fx4 fv = *(const fx4*)(x + (size_t)(r0 + row) * 256 + k0 + aseg * 4);
      ux2 p;
      p[0] = (unsigned)(unsigned short)f2bf(fv[0]) | ((unsigned)(unsigned short)f2bf(fv[1]) << 16);
      p[1] = (unsigned)(unsigned short)f2bf(fv[2]) | ((unsigned)(unsigned short)f2bf(fv[3]) << 16);
      int addr = (row * 64 + aseg * 8) ^ ((row & 7) << 4);
      *(ux2*)(smA + addr) = p;
    }
    #pragma unroll
    for (int q = 0; q < 4; ++q) {
      fx4 fv = *(const fx4*)(W_in + (size_t)(k0 + bk) * HID + c0 + q * 32 + bq * 4);
      #pragma unroll
      for (int e = 0; e < 4; ++e) {
        int col = q * 32 + bq * 4 + e;
        int addr = (col * 64 + bk * 2) ^ ((col & 7) << 4);
        *(short*)(smB + addr) = f2bf(fv[e]);
      }
    }
    __syncthreads();
    bf16x8 af[4];
    #pragma unroll
    for (int mt = 0; mt < 4; ++mt) {
      int row = wm * 64 + mt * 16 + lr;
      af[mt] = *(const bf16x8*)(smA + ((row * 64 + lg * 16) ^ ((row & 7) << 4)));
    }
    #pragma unroll
    for (int nt = 0; nt < 4; ++nt) {
      int col = wn * 64 + nt * 16 + lr;
      bf16x8 bf = *(const bf16x8*)(smB + ((col * 64 + lg * 16) ^ ((col & 7) << 4)));
      #pragma unroll
      for (int mt = 0; mt < 4; ++mt)
        acc[mt][nt] = __builtin_amdgcn_mfma_f32_16x16x32_bf16(af[mt], bf, acc[mt][nt], 0, 0, 0);
    }
    __syncthreads();
  }
  float bi[4];
  #pragma unroll
  for (int nt = 0; nt < 4; ++nt) {
    int c = c0 + wn * 64 + nt * 16 + lr;
    bi[nt] = b_in[c] + b_hid[c];
  }
  #pragma unroll
  for (int mt = 0; mt < 4; ++mt)
    #pragma unroll
    for (int nt = 0; nt < 4; ++nt)
      #pragma unroll
      for (int jj = 0; jj < 4; ++jj) {
        int grow = r0 + wm * 64 + mt * 16 + lg * 4 + jj;
        int gcol = c0 + wn * 64 + nt * 16 + lr;
        out[(size_t)grow * HID + gcol] = acc[mt][nt][jj] + bi[nt];
      }
}

// ---------------- Kernel P: pack W_hid tile-2 fragments into d_ws (128 KB) ----------------
// frag(w, kk, lane=(lg,lr)) = W_hid[kk*32+lg*8 .. +8][w*64+32+lr], bf16x8, linear by (w,kk,lane).
__global__ __launch_bounds__(512) void pack_w(const float* __restrict__ W_hid,
                                              short* __restrict__ ws)
{
  const int tid = threadIdx.x;
  const int wave = tid >> 6, lane = tid & 63;
  const int lg = lane >> 4, lr = lane & 15;
  const int col = wave * 64 + 32 + lr;
  for (int kk = 0; kk < 16; ++kk) {
    bf16x8 w;
    #pragma unroll
    for (int j = 0; j < 8; ++j)
      w[j] = f2bf(W_hid[(size_t)(kk * 32 + lg * 8 + j) * HID + col]);
    *(bf16x8*)(ws + ((size_t)((wave * 16 + kk) * 64 + lane)) * 8) = w;
  }
}

// ---------------- Kernel B: persistent recurrent scan (flipped MFMA) ----------------
// 4 WGs x 16 batches, 8 waves/WG, wave owns 64 output cols (4 n-tiles of 16):
//   tiles 0,1 -> regs (128); tile 2 -> 8-slot rolling L2 stream; tile 3 -> LDS fragments.
// MFMA: A = W fragment, B = fr fragment  =>  thread owns (batch = lr, h = cb+nt*16+lg*4+reg):
//   global vin/store = 4x dwordx4; fr-frag LDS writes = 4x ds_write_b64 (2-way, free).
// All LDS reads are fragment-linear (addr = base + kk*1024 + lane*16): conflict-free.
// LDS: [0,128K) W tile3 frags [wave][kk][lane]; [128K,144K) fr frag buf0; [144K,160K) buf1.
#define FR0_OFF (128 * 1024)

__global__ __launch_bounds__(512, 2) void rnn_scan(
    float* base,                                  // d_out: vin in, fr out (aliases!)
    const float* __restrict__ init_state,
    const float* __restrict__ W_hid,
    const float* __restrict__ alpha,
    const short* __restrict__ wsf)                // packed tile-2 fragments
{
  extern __shared__ __align__(16) char smem[];
  const int tid = threadIdx.x;
  const int wave = tid >> 6, lane = tid & 63;
  const int lg = lane >> 4, lr = lane & 15;
  const int bwg = blockIdx.x;
  const int cb = wave * 64;

  // ---- weights: n-tiles 0,1 -> regs ----
  bf16x8 wreg[2][16];
  #pragma unroll
  for (int nt = 0; nt < 2; ++nt) {
    const int col = cb + nt * 16 + lr;
    #pragma unroll
    for (int kk = 0; kk < 16; ++kk) {
      const int k0 = kk * 32 + lg * 8;
      bf16x8 w;
      #pragma unroll
      for (int j = 0; j < 8; ++j)
        w[j] = f2bf(W_hid[(size_t)(k0 + j) * HID + col]);
      wreg[nt][kk] = w;
    }
  }
  // ---- tile 3 -> LDS fragments, each thread writes its own lane's fragment ----
  {
    const int col = cb + 48 + lr;
    for (int kk = 0; kk < 16; ++kk) {
      bf16x8 w;
      #pragma unroll
      for (int j = 0; j < 8; ++j)
        w[j] = f2bf(W_hid[(size_t)(kk * 32 + lg * 8 + j) * HID + col]);
      *(bf16x8*)(smem + wave * 16384 + kk * 1024 + lane * 16) = w;
    }
  }

  // per-thread h-offsets: h0(nt) = cb + nt*16 + lg*4  (batch = lr)
  int hoff[4];
  #pragma unroll
  for (int nt = 0; nt < 4; ++nt) hoff[nt] = cb + nt * 16 + lg * 4;

  // alpha, packed as bf16 pairs (8 regs)
  unsigned al2[8];
  #pragma unroll
  for (int nt = 0; nt < 4; ++nt) {
    fx4 a4 = *(const fx4*)(alpha + hoff[nt]);
    al2[nt * 2]     = (unsigned)(unsigned short)f2bf(a4[0]) | ((unsigned)(unsigned short)f2bf(a4[1]) << 16);
    al2[nt * 2 + 1] = (unsigned)(unsigned short)f2bf(a4[2]) | ((unsigned)(unsigned short)f2bf(a4[3]) << 16);
  }

  // v init
  float v[4][4];
  #pragma unroll
  for (int nt = 0; nt < 4; ++nt) {
    fx4 iv = *(const fx4*)(init_state + (size_t)(bwg * 16 + lr) * HID + hoff[nt]);
    #pragma unroll
    for (int j = 0; j < 4; ++j) v[nt][j] = iv[j];
  }

  // fr-fragment write addresses (byte, within a buffer)
  int fw[4];
  #pragma unroll
  for (int nt = 0; nt < 4; ++nt)
    fw[nt] = (wave * 2 + (nt >> 1)) * 1024 + ((((nt & 1) * 2 + (lg >> 1)) * 16 + lr) * 16) + ((lg & 1) * 8);

  // fr0 = relu(v0) fragments into buffer 0
  #pragma unroll
  for (int nt = 0; nt < 4; ++nt) {
    ux2 pw;
    pw[0] = (unsigned)(unsigned short)f2bf(fmaxf(v[nt][0], 0.f)) |
            ((unsigned)(unsigned short)f2bf(fmaxf(v[nt][1], 0.f)) << 16);
    pw[1] = (unsigned)(unsigned short)f2bf(fmaxf(v[nt][2], 0.f)) |
            ((unsigned)(unsigned short)f2bf(fmaxf(v[nt][3], 0.f)) << 16);
    *(ux2*)(smem + FR0_OFF + fw[nt]) = pw;
  }

  // global base for this thread's batch row
  float* bb = base + (size_t)(bwg * 16 + lr) * TSTEPS * HID;

  // vin t=0
  fx4 vld[4];
  #pragma unroll
  for (int nt = 0; nt < 4; ++nt) vld[nt] = *(const fx4*)(bb + hoff[nt]);

  // tile-2 stream: 8-slot rolling window over 16 constant fragments
  const bf16x8* wsp = (const bf16x8*)wsf + ((size_t)wave * 16 * 64 + lane);
  bf16x8 wst[8];
  #pragma unroll
  for (int s = 0; s < 8; ++s) wst[s] = wsp[s * 64];

  __syncthreads();

  const int wldsbase = wave * 16384 + lane * 16;
  const int frrd = lane * 16;

  for (int t = 0; t < TSTEPS; ++t) {
    const int rb = FR0_OFF + ((t & 1) << 14);
    const int wbuf = FR0_OFF + (((t + 1) & 1) << 14);
    const int tn = (t + 1 < TSTEPS) ? t + 1 : t;   // clamp: last prefetch stays in-bounds

    fx4 acc[4];
    #pragma unroll
    for (int nt = 0; nt < 4; ++nt) acc[nt] = vld[nt];

    #pragma unroll
    for (int kk = 0; kk < 16; ++kk) {
      bf16x8 fb = *(const bf16x8*)(smem + rb + kk * 1024 + frrd);
      bf16x8 w3 = *(const bf16x8*)(smem + wldsbase + kk * 1024);
      acc[0] = __builtin_amdgcn_mfma_f32_16x16x32_bf16(wreg[0][kk], fb, acc[0], 0, 0, 0);
      acc[1] = __builtin_amdgcn_mfma_f32_16x16x32_bf16(wreg[1][kk], fb, acc[1], 0, 0, 0);
      acc[2] = __builtin_amdgcn_mfma_f32_16x16x32_bf16(wst[kk & 7], fb, acc[2], 0, 0, 0);
      acc[3] = __builtin_amdgcn_mfma_f32_16x16x32_bf16(w3, fb, acc[3], 0, 0, 0);
      // scheduled loads (all mid-loop so the barrier never drains fresh traffic):
      if (kk < 8)  wst[kk] = wsp[(kk + 8) * 64];          // this step's kk 8..15
      if (kk >= 4 && kk < 8) vld[kk - 4] = *(const fx4*)(bb + (size_t)tn * HID + hoff[kk - 4]);
      if (kk >= 9) wst[kk - 9] = wsp[(kk - 9) * 64];      // next step's kk 0..6
    }

    // v update + relu + vectorized global store + fragment LDS write
    #pragma unroll
    for (int nt = 0; nt < 4; ++nt) {
      fx4 st;
      #pragma unroll
      for (int j = 0; j < 4; ++j) {
        unsigned u = al2[nt * 2 + (j >> 1)];
        float aj = __builtin_bit_cast(float, (j & 1) ? (u & 0xffff0000u) : (u << 16));
        float nv = v[nt][j] + aj * (acc[nt][j] - v[nt][j]);
        v[nt][j] = nv;
        st[j] = fmaxf(nv, 0.f);
      }
      *(fx4*)(bb + (size_t)t * HID + hoff[nt]) = st;
      ux2 pw;
      pw[0] = (unsigned)(unsigned short)f2bf(st[0]) | ((unsigned)(unsigned short)f2bf(st[1]) << 16);
      pw[1] = (unsigned)(unsigned short)f2bf(st[2]) | ((unsigned)(unsigned short)f2bf(st[3]) << 16);
      *(ux2*)(smem + wbuf + fw[nt]) = pw;
    }

    wst[7] = wsp[7 * 64];    // next step's kk 7 (single residual pre-barrier load)

    __syncthreads();
  }
}

extern "C" void kernel_launch(void* const* d_in, const int* in_sizes, int n_in,
                              void* d_out, int out_size, void* d_ws, size_t ws_size,
                              hipStream_t stream) {
  const float* x     = (const float*)d_in[0];
  const float* inist = (const float*)d_in[1];
  const float* W_in  = (const float*)d_in[2];
  const float* b_in  = (const float*)d_in[3];
  const float* W_hid = (const float*)d_in[4];
  const float* b_hid = (const float*)d_in[5];
  const float* alph  = (const float*)d_in[6];
  float* out = (float*)d_out;
  (void)in_sizes; (void)n_in; (void)out_size; (void)ws_size;

  pack_w<<<dim3(1), dim3(512), 0, stream>>>(W_hid, (short*)d_ws);
  vin_gemm<<<dim3(512, 4), dim3(256), 0, stream>>>(x, W_in, b_in, b_hid, out);

  (void)hipFuncSetAttribute(reinterpret_cast<const void*>(rnn_scan),
                            hipFuncAttributeMaxDynamicSharedMemorySize, 160 * 1024);
  rnn_scan<<<dim3(4), dim3(512), 160 * 1024, stream>>>(out, inist, W_hid, alph,
                                                       (const short*)d_ws);
}